// Round 5
// baseline (196.827 us; speedup 1.0000x reference)
//
#include <hip/hip_runtime.h>
#include <hip/hip_bf16.h>
#include <stdint.h>

#define IN_F 128
#define EDGE_F 6
#define TILE_E 4096      // hist/scatter tile; K1 hist blocks and K2 blocks MUST share this mapping
#define NBIN_PAD 256     // coarse bins = dst>>8 (n_nodes <= 65536 assumed; N=50000 -> 196 bins)
#define PADMAX 1792      // 256 dsts * 7 max pad records per dst (pad deg to multiple of 8)
#define K1_BLOCKS 2048   // cast/hist grid (weight block rides at index K1_BLOCKS)

using bf16x8 = __attribute__((ext_vector_type(8))) short;  // 8 bf16 = 4 VGPRs
using f32x4  = __attribute__((ext_vector_type(4))) float;

__device__ __forceinline__ float bf2f(unsigned short u) {
    return __uint_as_float(((unsigned int)u) << 16);
}
__device__ __forceinline__ unsigned short f2bfbits(float f) {
    __hip_bfloat16 h = __float2bfloat16(f);  // RNE
    return *reinterpret_cast<unsigned short*>(&h);
}
__device__ __forceinline__ unsigned int packbf(float a, float b) {
    return ((unsigned int)f2bfbits(b) << 16) | (unsigned int)f2bfbits(a);
}

// ---- K1: nf cast + LDS-privatized coarse histogram + weight pack ----
// The efp payload pack is GONE (moved inline into K2's scatter), deleting a
// 12.8MB write + 12.8MB read round-trip. Blocks 0..nblk_e-1 count a 4096-edge
// tile into a 196-bin LDS histogram (cb = dst>>8) and write one 512B ushort
// row of the partial matrix. Block K1_BLOCKS does the weight pack + zeroes
// the dummy nf row. ZERO scattered global atomics.
__global__ __launch_bounds__(256) void hist_cast(
        const int* __restrict__ eidx, unsigned short* __restrict__ pmat,
        int n_edges, int nblk_e, int n_cast, int wblk, int n_nodes,
        const float* __restrict__ nf, unsigned short* __restrict__ nfb,
        const float* __restrict__ W, const float* __restrict__ b,
        const float* __restrict__ We, const float* __restrict__ be,
        unsigned short* __restrict__ Wpack, float* __restrict__ W2pack) {
    const int tid = threadIdx.x;
    const int blk = blockIdx.x;
    __shared__ int hist[NBIN_PAD];

    if (blk == wblk) {
        // Wpack: idx=((kb*8+ft)*64+lane)*8+j -> bf16(W[kb*32+(lane>>4)*8+j][ft*16+(lane&15)])
        for (int idx = tid; idx < 16384; idx += 256) {
            int j = idx & 7, lane = (idx >> 3) & 63, ft = (idx >> 9) & 7, kb = idx >> 12;
            int k = kb * 32 + (lane >> 4) * 8 + j;
            int f = ft * 16 + (lane & 15);
            Wpack[idx] = f2bfbits(W[k * 128 + f]);
        }
        for (int idx = tid; idx < 1024; idx += 256) {
            int j = idx >> 7, f = idx & 127;
            float w = 0.f;
            if (j < 6)       w = We[j * 128 + f];
            else if (j == 6) w = b[f] + be[f];
            W2pack[idx] = w;
        }
        // dummy node row (index n_nodes): zero. Pad records gather from here --
        // one 256B hot line, adds 0.0 to every sum.
        if (tid < 16) {
            uint4 z; z.x = z.y = z.z = z.w = 0u;
            reinterpret_cast<uint4*>(nfb + (size_t)n_nodes * IN_F)[tid] = z;
        }
    } else if (blk < nblk_e) {
        hist[tid] = 0;
        __syncthreads();
        const int e0 = blk * TILE_E;
#pragma unroll
        for (int i = 0; i < TILE_E / 256; ++i) {
            const int e = e0 + i * 256 + tid;
            if (e < n_edges) {
                const int dst = reinterpret_cast<const int2*>(eidx)[e].y;
                atomicAdd(&hist[dst >> 8], 1);
            }
        }
        __syncthreads();
        pmat[(size_t)blk * NBIN_PAD + tid] = (unsigned short)hist[tid];
    }
    // nf -> bf16 cast rides along (grid-stride over all blocks)
    const int t = blk * 256 + tid;
    const int stride = gridDim.x * 256;
    for (int i = t; i < n_cast; i += stride) {
        const float4 lo = reinterpret_cast<const float4*>(nf)[2 * i];
        const float4 hi = reinterpret_cast<const float4*>(nf)[2 * i + 1];
        uint4 o;
        o.x = packbf(lo.x, lo.y); o.y = packbf(lo.z, lo.w);
        o.z = packbf(hi.x, hi.y); o.w = packbf(hi.z, hi.w);
        reinterpret_cast<uint4*>(nfb)[i] = o;
    }
}

// ---- K2: inline pack + coarse scatter into dst>>8 buckets. No global atomics. ----
// Each block reconstructs its per-bin start cursor from the partial matrix
// (100 KB, L2-broadcast): cursor[c] = base[c] + sum_{b'<blk} pmat[b'][c].
// Same tile mapping as K1's hist blocks -> counts match scatters exactly ->
// slots form a bijection. Reads eidx+ef directly (coalesced) and packs the
// 16B record inline -- the efp intermediate is deleted. src,dst < 65536 so
// dst rides in the high half of q.x; downstream never re-reads eidx.
__global__ __launch_bounds__(256) void pack_scatter(
        const int* __restrict__ eidx, const float* __restrict__ ef,
        const unsigned short* __restrict__ pmat,
        uint4* __restrict__ rec_c, int* __restrict__ gbase,
        int n_edges, int nblk_e, int nbin) {
    const int tid = threadIdx.x;
    const int blk = blockIdx.x;
    __shared__ int cur[NBIN_PAD];
    __shared__ int sc[NBIN_PAD];
    int tot = 0, pre = 0;
#pragma unroll 4
    for (int bb = 0; bb < nblk_e; ++bb) {
        const int v = pmat[(size_t)bb * NBIN_PAD + tid];
        tot += v;
        pre += (bb < blk) ? v : 0;
    }
    sc[tid] = tot;
    __syncthreads();
    for (int off = 1; off < 256; off <<= 1) {  // inclusive scan of totals
        int t2 = (tid >= off) ? sc[tid - off] : 0;
        __syncthreads();
        sc[tid] += t2;
        __syncthreads();
    }
    const int excl = sc[tid] - tot;            // base[tid]
    cur[tid] = excl + pre;
    if (blk == 0 && tid <= nbin) gbase[tid] = excl;  // gbase[nbin] == n_edges
    __syncthreads();
    const int e0 = blk * TILE_E;
#pragma unroll
    for (int i = 0; i < TILE_E / 256; ++i) {
        const int e = e0 + i * 256 + tid;
        if (e < n_edges) {
            const int2 pr = reinterpret_cast<const int2*>(eidx)[e];  // (src, dst)
            const float2* efs = reinterpret_cast<const float2*>(ef + (size_t)e * EDGE_F);
            const float2 f0 = efs[0], f1 = efs[1], f2 = efs[2];
            uint4 q;
            q.x = (unsigned int)pr.x | ((unsigned int)pr.y << 16);
            q.y = packbf(f0.x, f0.y);
            q.z = packbf(f1.x, f1.y);
            q.w = packbf(f2.x, f2.y);
            const int pos = atomicAdd(&cur[pr.y >> 8], 1);
            rec_c[pos] = q;                    // ~21-edge (336B) run locality
        }
    }
}

// ---- K3: bucket-local fine counting sort -> PADDED CSR rec + pr2 ----
// One block per 256-node bucket (~4082 edges, L2-hot; 2 passes). All ranking
// via LDS. Each dst's run in rec is padded to a multiple of 8 with dummy
// records (src = n_nodes -> zero row), so the aggregate kernel runs ONLY
// full 8-record batches. Padded bucket base = gbase[c] + c*PADMAX, provably
// disjoint since per-bucket pad <= 256*7. pr2[n] = {padded_start, true_deg}.
__global__ __launch_bounds__(256) void fine_rank(
        const uint4* __restrict__ rec_c, const int* __restrict__ gbase,
        uint4* __restrict__ rec, int2* __restrict__ pr2, int n_nodes) {
    const int tid = threadIdx.x;
    const int c = blockIdx.x;
    const int rbase = gbase[c], rend = gbase[c + 1];
    const int pbase = rbase + c * PADMAX;
    __shared__ int fcnt[256];
    __shared__ int fpos[256];
    fcnt[tid] = 0;
    __syncthreads();
    for (int i = rbase + tid; i < rend; i += 256) {
        const unsigned int qx = reinterpret_cast<const unsigned int*>(rec_c)[(size_t)i * 4];
        atomicAdd(&fcnt[(qx >> 16) & 255], 1);
    }
    __syncthreads();
    const int own = fcnt[tid];
    const int ownp = (own + 7) & ~7;           // padded run length
    fcnt[tid] = ownp;
    __syncthreads();
    for (int off = 1; off < 256; off <<= 1) {  // inclusive scan of padded lengths
        int t2 = (tid >= off) ? fcnt[tid - off] : 0;
        __syncthreads();
        fcnt[tid] += t2;
        __syncthreads();
    }
    const int pexcl = fcnt[tid] - ownp;        // padded exclusive prefix
    fpos[tid] = pexcl;
    const int n = c * 256 + tid;
    if (n < n_nodes) {
        int2 pr; pr.x = pbase + pexcl; pr.y = own;
        pr2[n] = pr;
    }
    __syncthreads();
    for (int i = rbase + tid; i < rend; i += 256) {
        const uint4 q = rec_c[i];                          // L2-hot re-read
        const int r = atomicAdd(&fpos[(q.x >> 16) & 255], 1);
        rec[pbase + r] = q;
    }
    // pad fill: thread tid owns dst tid's <=7 dummy slots (16B writes, 64KB window)
    uint4 dmy; dmy.x = (unsigned int)n_nodes; dmy.y = dmy.z = dmy.w = 0u;
    for (int j = own; j < ownp; ++j)
        rec[pbase + pexcl + j] = dmy;
}

// ---- K4: aggregate. One wave per dst; HALF-WAVE pair gather (8B/lane). ----
// rec[i] loads are wave-uniform -> SGPRs. Every dst run is a multiple of 8
// records; each batch issues 4 dwordx2 gathers covering 8 edges (lanes 0-31 ->
// edge 2p, lanes 32-63 -> edge 2p+1): same bytes in flight as 8 dword gathers
// but HALF the vector-memory instructions / TCC requests. Feature partials
// are folded once per dst with 4 shfl_xor(32). Max-occupancy kernel; do NOT
// fuse with the MFMA gemm (R12: fusion collapses wave count and doubles time).
__global__ __launch_bounds__(256) void aggregate_bf16(
        const unsigned short* __restrict__ nfb, const uint4* __restrict__ rec,
        const int2* __restrict__ pr2, unsigned short* __restrict__ S,
        unsigned short* __restrict__ E8, int n_nodes) {
    const int lane = threadIdx.x & 63;
    const int wv = __builtin_amdgcn_readfirstlane(threadIdx.x >> 6);
    const int n = blockIdx.x * 4 + wv;
    if (n >= n_nodes) return;
    const int2 pr = pr2[n];
    const int deg = pr.y;
    const int nb = (deg + 7) >> 3;             // all batches full (padded)
    const int half = lane >> 5;                // 0: edge 2p, 1: edge 2p+1
    const int hl = lane & 31;                  // owns feats 4*hl .. 4*hl+3
    float a0 = 0.f, a1 = 0.f, a2 = 0.f, a3 = 0.f;
    float e0 = 0.f, e1 = 0.f, e2 = 0.f, e3 = 0.f, e4 = 0.f, e5 = 0.f;
    int i = pr.x;
    for (int bb = 0; bb < nb; ++bb, i += 8) {
        uint4 q[8];
#pragma unroll
        for (int j = 0; j < 8; ++j) q[j] = rec[i + j];           // SGPR, wave-uniform
        uint2 u[4];
#pragma unroll
        for (int p = 0; p < 4; ++p) {
            const unsigned int sA = q[2 * p].x & 0xFFFFu;
            const unsigned int sB = q[2 * p + 1].x & 0xFFFFu;
            const unsigned int s = half ? sB : sA;
            u[p] = reinterpret_cast<const uint2*>(nfb + (size_t)s * IN_F)[hl];
        }
#pragma unroll
        for (int p = 0; p < 4; ++p) {
            a0 += bf2f((unsigned short)u[p].x);
            a1 += bf2f((unsigned short)(u[p].x >> 16));
            a2 += bf2f((unsigned short)u[p].y);
            a3 += bf2f((unsigned short)(u[p].y >> 16));
        }
#pragma unroll
        for (int j = 0; j < 8; ++j) {
            e0 += bf2f((unsigned short)q[j].y);
            e1 += bf2f((unsigned short)(q[j].y >> 16));
            e2 += bf2f((unsigned short)q[j].z);
            e3 += bf2f((unsigned short)(q[j].z >> 16));
            e4 += bf2f((unsigned short)q[j].w);
            e5 += bf2f((unsigned short)(q[j].w >> 16));
        }
    }
    // fold the two half-wave partials (feats only; e-sums were whole-wave)
    a0 += __shfl_xor(a0, 32, 64);
    a1 += __shfl_xor(a1, 32, 64);
    a2 += __shfl_xor(a2, 32, 64);
    a3 += __shfl_xor(a3, 32, 64);
    if (half == 0) {
        uint2 o;
        o.x = packbf(a0, a1);
        o.y = packbf(a2, a3);
        reinterpret_cast<uint2*>(S + (size_t)n * IN_F)[hl] = o;   // 256B row, 32 lanes
    }
    if (lane == 0) {
        uint4 q;
        q.x = packbf(e0, e1);
        q.y = packbf(e2, e3);
        q.z = packbf(e4, e5);
        q.w = packbf((float)deg, 0.f);          // deg exact in bf16 (small)
        *reinterpret_cast<uint4*>(E8 + (size_t)n * 8) = q;
    }
}

// ---- K5: MFMA GEMM  out = relu( S[N,128]bf16 @ W[128,128]bf16 + E-term ) ----
__global__ __launch_bounds__(256) void gemm_mfma(
        const unsigned short* __restrict__ S, const unsigned short* __restrict__ E8,
        const unsigned short* __restrict__ Wpack, const float* __restrict__ W2pack,
        float* __restrict__ out, int n_nodes) {
    __shared__ __align__(16) short Wl[16384];   // 32 KB, B-fragment layout
    __shared__ float W2l[1024];                 // 4 KB
    const int tid = threadIdx.x;
    for (int i = tid; i < 2048; i += 256)
        reinterpret_cast<uint4*>(Wl)[i] = reinterpret_cast<const uint4*>(Wpack)[i];
    for (int i = tid; i < 1024; i += 256) W2l[i] = W2pack[i];

    const int wv = tid >> 6, lane = tid & 63;
    const int m = lane & 15, quad = lane >> 4;
    const int n0 = blockIdx.x * 64 + wv * 16;

    const int arow = min(n0 + m, n_nodes - 1);
    const unsigned short* ap = S + (size_t)arow * IN_F + quad * 8;
    bf16x8 a[4];
#pragma unroll
    for (int kb = 0; kb < 4; ++kb)
        a[kb] = *reinterpret_cast<const bf16x8*>(ap + kb * 32);

    __syncthreads();

    f32x4 acc[8];
#pragma unroll
    for (int ft = 0; ft < 8; ++ft) acc[ft] = (f32x4){0.f, 0.f, 0.f, 0.f};

#pragma unroll
    for (int kb = 0; kb < 4; ++kb) {
#pragma unroll
        for (int ft = 0; ft < 8; ++ft) {
            const bf16x8 bfrag =
                reinterpret_cast<const bf16x8*>(Wl)[(kb * 8 + ft) * 64 + lane];
            acc[ft] = __builtin_amdgcn_mfma_f32_16x16x32_bf16(a[kb], bfrag, acc[ft], 0, 0, 0);
        }
    }

    // Epilogue. C/D layout: col=lane&15, row=quad*4+reg.
    float e[4][7];
#pragma unroll
    for (int r = 0; r < 4; ++r) {
        const int n = min(n0 + quad * 4 + r, n_nodes - 1);
        const uint4 q = *reinterpret_cast<const uint4*>(E8 + (size_t)n * 8);
        e[r][0] = bf2f((unsigned short)q.x); e[r][1] = bf2f((unsigned short)(q.x >> 16));
        e[r][2] = bf2f((unsigned short)q.y); e[r][3] = bf2f((unsigned short)(q.y >> 16));
        e[r][4] = bf2f((unsigned short)q.z); e[r][5] = bf2f((unsigned short)(q.z >> 16));
        e[r][6] = bf2f((unsigned short)q.w);  // deg
    }
#pragma unroll
    for (int ft = 0; ft < 8; ++ft) {
        const int f = ft * 16 + m;
        float w2[7];
#pragma unroll
        for (int j = 0; j < 7; ++j) w2[j] = W2l[j * 128 + f];
#pragma unroll
        for (int r = 0; r < 4; ++r) {
            const int n = n0 + quad * 4 + r;
            if (n < n_nodes) {
                float v = acc[ft][r];
#pragma unroll
                for (int j = 0; j < 7; ++j) v += e[r][j] * w2[j];
                out[(size_t)n * 128 + f] = fmaxf(v, 0.f);
            }
        }
    }
}

extern "C" void kernel_launch(void* const* d_in, const int* in_sizes, int n_in,
                              void* d_out, int out_size, void* d_ws, size_t ws_size,
                              hipStream_t stream) {
    const float* nf = (const float*)d_in[0];  // fp32 (N,128)
    const int* eidx = (const int*)d_in[1];    // int32 (E,2)
    const float* ef = (const float*)d_in[2];  // fp32 (E,6)
    const float* W  = (const float*)d_in[3];  // fp32 (128,128)
    const float* b  = (const float*)d_in[4];  // fp32 (128,)
    const float* We = (const float*)d_in[5];  // fp32 (6,128)
    const float* be = (const float*)d_in[6];  // fp32 (128,)
    float* out = (float*)d_out;               // fp32 (N,128)

    const int n_nodes = in_sizes[0] / IN_F;
    const int n_edges = in_sizes[1] / 2;

    const int nblk_e = (n_edges + TILE_E - 1) / TILE_E;   // 196 hist/scatter blocks
    const int nbin = (n_nodes + 255) >> 8;                // 196 coarse buckets
    const int n_cast = n_nodes * (IN_F / 8);

    // ws (~45 MB): rec (E + nbin*PADMAX recs, padded CSR) | rec_c
    //   | S | E8 | Wpack | W2pack | pmat | gbase | pr2 | nfb ((N+1) rows)
    // efp is GONE (packing is inline in pack_scatter).
    uint4* rec   = (uint4*)d_ws;
    uint4* rec_c = rec + ((size_t)n_edges + (size_t)nbin * PADMAX);
    unsigned short* S = (unsigned short*)(rec_c + n_edges);
    unsigned short* E8 = S + (size_t)n_nodes * IN_F;
    unsigned short* Wpack = E8 + (size_t)n_nodes * 8;
    float* W2pack = (float*)(Wpack + 16384);
    unsigned short* pmat = (unsigned short*)(W2pack + 1024);
    int* gbase = (int*)(pmat + (size_t)nblk_e * NBIN_PAD);
    int2* pr2 = (int2*)(gbase + 260);
    unsigned short* nfb = (unsigned short*)(pr2 + n_nodes);

    // No memset needed: pmat rows fully written, all cursors derived in-LDS,
    // pad records explicitly written by fine_rank.
    hist_cast<<<K1_BLOCKS + 1, 256, 0, stream>>>(eidx, pmat,
                                                 n_edges, nblk_e, n_cast, K1_BLOCKS,
                                                 n_nodes, nf, nfb,
                                                 W, b, We, be, Wpack, W2pack);
    pack_scatter<<<nblk_e, 256, 0, stream>>>(eidx, ef, pmat, rec_c, gbase,
                                             n_edges, nblk_e, nbin);
    fine_rank<<<nbin, 256, 0, stream>>>(rec_c, gbase, rec, pr2, n_nodes);
    aggregate_bf16<<<(n_nodes + 3) / 4, 256, 0, stream>>>(nfb, rec, pr2, S, E8, n_nodes);
    gemm_mfma<<<(n_nodes + 63) / 64, 256, 0, stream>>>(S, E8, Wpack, W2pack, out, n_nodes);
}

// Round 6
// 195.386 us; speedup vs baseline: 1.0074x; 1.0074x over previous
//
#include <hip/hip_runtime.h>
#include <hip/hip_bf16.h>
#include <stdint.h>

#define IN_F 128
#define EDGE_F 6
#define TILE_E 4096      // per-block sort tile (block-local, no cross-block mapping needed)
#define NBIN_PAD 256     // coarse bins = dst>>8 (n_nodes <= 65536; N=50000 -> 196 used)
#define BCAP 8192        // padded records per bucket (mean ~4082+pad<=1792; ~60 sigma margin)
#define CAST_B 400       // dedicated cast blocks riding in the K1 grid

using bf16x8 = __attribute__((ext_vector_type(8))) short;  // 8 bf16 = 4 VGPRs
using f32x4  = __attribute__((ext_vector_type(4))) float;

__device__ __forceinline__ float bf2f(unsigned short u) {
    return __uint_as_float(((unsigned int)u) << 16);
}
__device__ __forceinline__ unsigned short f2bfbits(float f) {
    __hip_bfloat16 h = __float2bfloat16(f);  // RNE
    return *reinterpret_cast<unsigned short*>(&h);
}
__device__ __forceinline__ unsigned int packbf(float a, float b) {
    return ((unsigned int)f2bfbits(b) << 16) | (unsigned int)f2bfbits(a);
}

// ---- K1: block-LOCAL counting sort + inline pack + nf cast + weight pack ----
// Replaces hist_cast + pack_scatter. Each sort block owns tile blk*TILE_E and
// its own output segment rec_c[blk*TILE_E ...]: hist its 4096 edges into 256
// coarse bins (LDS), scan locally, scatter packed records into bin-grouped
// order WITHIN its segment (64KB window, coalesced-ish). No pmat broadcast,
// no global scan, no cross-block coordination of any kind -- the global
// bucket assembly moves to fine_rank, which reads the per-(block,bin) runs
// via pmat (counts) + lmat (local offsets). Cast blocks and the weight-pack
// block ride in the same grid (fully independent work).
__global__ __launch_bounds__(256) void sort_pack_cast(
        const int* __restrict__ eidx, const float* __restrict__ ef,
        uint4* __restrict__ rec_c, unsigned short* __restrict__ pmat,
        unsigned short* __restrict__ lmat,
        int n_edges, int nblk_e, int n_cast, int n_nodes,
        const float* __restrict__ nf, unsigned short* __restrict__ nfb,
        const float* __restrict__ W, const float* __restrict__ b,
        const float* __restrict__ We, const float* __restrict__ be,
        unsigned short* __restrict__ Wpack, float* __restrict__ W2pack) {
    const int tid = threadIdx.x;
    const int blk = blockIdx.x;
    __shared__ unsigned int qxs[TILE_E];   // 16 KB: packed src|dst<<16, staged once
    __shared__ int hist[NBIN_PAD];         // counts -> inclusive scan
    __shared__ int cur[NBIN_PAD];          // scatter cursors

    if (blk < nblk_e) {
        hist[tid] = 0;
        __syncthreads();
        const int e0 = blk * TILE_E;
        const int lim = min(TILE_E, n_edges - e0);
        // pass A: stage qx in LDS + LDS hist (eidx read ONCE)
        for (int i = tid; i < lim; i += 256) {
            const int2 pr = reinterpret_cast<const int2*>(eidx)[e0 + i];  // (src,dst)
            const unsigned int q = (unsigned int)pr.x | ((unsigned int)pr.y << 16);
            qxs[i] = q;
            atomicAdd(&hist[q >> 24], 1);          // q>>24 == dst>>8
        }
        __syncthreads();
        const int own = hist[tid];
        for (int off = 1; off < 256; off <<= 1) {  // inclusive scan of bin counts
            int t2 = (tid >= off) ? hist[tid - off] : 0;
            __syncthreads();
            hist[tid] += t2;
            __syncthreads();
        }
        const int excl = hist[tid] - own;          // local bin offset
        pmat[(size_t)blk * NBIN_PAD + tid] = (unsigned short)own;
        lmat[(size_t)blk * NBIN_PAD + tid] = (unsigned short)excl;
        cur[tid] = excl;
        __syncthreads();
        // pass B: read ef (coalesced), pack 16B record, scatter into OWN segment
        uint4* seg = rec_c + (size_t)blk * TILE_E;
        for (int i = tid; i < lim; i += 256) {
            const unsigned int q = qxs[i];
            const float2* efs = reinterpret_cast<const float2*>(ef + (size_t)(e0 + i) * EDGE_F);
            const float2 f0 = efs[0], f1 = efs[1], f2 = efs[2];
            uint4 r;
            r.x = q;
            r.y = packbf(f0.x, f0.y);
            r.z = packbf(f1.x, f1.y);
            r.w = packbf(f2.x, f2.y);
            const int pos = atomicAdd(&cur[q >> 24], 1);
            seg[pos] = r;                          // 64KB window, bin-grouped
        }
    } else if (blk == nblk_e) {
        // Wpack: idx=((kb*8+ft)*64+lane)*8+j -> bf16(W[kb*32+(lane>>4)*8+j][ft*16+(lane&15)])
        for (int idx = tid; idx < 16384; idx += 256) {
            int j = idx & 7, lane = (idx >> 3) & 63, ft = (idx >> 9) & 7, kb = idx >> 12;
            int k = kb * 32 + (lane >> 4) * 8 + j;
            int f = ft * 16 + (lane & 15);
            Wpack[idx] = f2bfbits(W[k * 128 + f]);
        }
        for (int idx = tid; idx < 1024; idx += 256) {
            int j = idx >> 7, f = idx & 127;
            float w = 0.f;
            if (j < 6)       w = We[j * 128 + f];
            else if (j == 6) w = b[f] + be[f];
            W2pack[idx] = w;
        }
        // dummy node row (index n_nodes): zero. Pad records gather from here.
        if (tid < 16) {
            uint4 z; z.x = z.y = z.z = z.w = 0u;
            reinterpret_cast<uint4*>(nfb + (size_t)n_nodes * IN_F)[tid] = z;
        }
    } else {
        // cast block: nf -> bf16, vectorized (uint4 in / uint4 out)
        const int cb = blk - nblk_e - 1;
        const int ncb = gridDim.x - nblk_e - 1;
        for (int i = cb * 256 + tid; i < n_cast; i += ncb * 256) {
            const float4 lo = reinterpret_cast<const float4*>(nf)[2 * i];
            const float4 hi = reinterpret_cast<const float4*>(nf)[2 * i + 1];
            uint4 o;
            o.x = packbf(lo.x, lo.y); o.y = packbf(lo.z, lo.w);
            o.z = packbf(hi.x, hi.y); o.w = packbf(hi.z, hi.w);
            reinterpret_cast<uint4*>(nfb)[i] = o;
        }
    }
}

// ---- K2: bucket assembly + fine counting sort -> PADDED CSR rec + pr2 ----
// One block per 256-node bucket. Thread t owns block-t's run for this bucket:
// rec_c[t*TILE_E + lmat[t][c]], length pmat[t][c] (~21 records, L2-hot).
// Two passes over the runs (dst-hist, then scatter) through LDS ranking.
// Output at STATIC base c*BCAP (no gbase / no global scan). Each dst's run
// padded to a multiple of 8 with dummy records (src=n_nodes -> zero row) so
// the aggregate runs only full 8-record batches. pr2[n]={padded_start,deg}.
// Requires nblk_e <= 256 (196 here).
__global__ __launch_bounds__(256) void fine_rank(
        const uint4* __restrict__ rec_c, const unsigned short* __restrict__ pmat,
        const unsigned short* __restrict__ lmat,
        uint4* __restrict__ rec, int2* __restrict__ pr2,
        int n_nodes, int nblk_e) {
    const int tid = threadIdx.x;
    const int c = blockIdx.x;
    __shared__ int fcnt[256];
    __shared__ int fpos[256];
    const int cnt_t = (tid < nblk_e) ? pmat[(size_t)tid * NBIN_PAD + c] : 0;
    const int ofs_t = (tid < nblk_e) ? lmat[(size_t)tid * NBIN_PAD + c] : 0;
    const uint4* runp = rec_c + (size_t)tid * TILE_E + ofs_t;
    fcnt[tid] = 0;
    __syncthreads();
    for (int k = 0; k < cnt_t; ++k) {            // pass 1: dst histogram
        const unsigned int qx = reinterpret_cast<const unsigned int*>(runp)[4 * k];
        atomicAdd(&fcnt[(qx >> 16) & 255], 1);
    }
    __syncthreads();
    const int own = fcnt[tid];
    const int ownp = (own + 7) & ~7;             // padded run length
    fcnt[tid] = ownp;
    __syncthreads();
    for (int off = 1; off < 256; off <<= 1) {    // inclusive scan of padded lengths
        int t2 = (tid >= off) ? fcnt[tid - off] : 0;
        __syncthreads();
        fcnt[tid] += t2;
        __syncthreads();
    }
    const int pexcl = fcnt[tid] - ownp;          // padded exclusive prefix
    fpos[tid] = pexcl;
    const size_t obase = (size_t)c * BCAP;
    const int n = c * 256 + tid;
    if (n < n_nodes) {
        int2 pr; pr.x = (int)(obase + pexcl); pr.y = own;
        pr2[n] = pr;
    }
    __syncthreads();
    for (int k = 0; k < cnt_t; ++k) {            // pass 2: ranked scatter
        const uint4 q = runp[k];
        const int r = atomicAdd(&fpos[(q.x >> 16) & 255], 1);
        if (r < BCAP) rec[obase + r] = q;        // guard: ~60-sigma impossible
    }
    // pad fill: thread tid owns dst tid's <=7 dummy slots
    uint4 dmy; dmy.x = (unsigned int)n_nodes; dmy.y = dmy.z = dmy.w = 0u;
    for (int j = own; j < ownp && pexcl + j < BCAP; ++j)
        rec[obase + pexcl + j] = dmy;
}

// ---- K3: aggregate. One wave per dst; half-wave pair gather (8B/lane). ----
// rec[i] loads are wave-uniform -> SGPRs. Every dst run is a multiple of 8
// records; each batch issues 4 dwordx2 gathers covering 8 edges. The gather
// is TCC/LLC byte-throughput-bound (R2 scaling + R4 pad-null + R5 pair-null
// all agree) -- do not spend more rounds on its concurrency. Max-occupancy
// kernel; do NOT fuse with the MFMA gemm (R12).
__global__ __launch_bounds__(256) void aggregate_bf16(
        const unsigned short* __restrict__ nfb, const uint4* __restrict__ rec,
        const int2* __restrict__ pr2, unsigned short* __restrict__ S,
        unsigned short* __restrict__ E8, int n_nodes) {
    const int lane = threadIdx.x & 63;
    const int wv = __builtin_amdgcn_readfirstlane(threadIdx.x >> 6);
    const int n = blockIdx.x * 4 + wv;
    if (n >= n_nodes) return;
    const int2 pr = pr2[n];
    const int deg = pr.y;
    const int nb = (deg + 7) >> 3;             // all batches full (padded)
    const int half = lane >> 5;                // 0: edge 2p, 1: edge 2p+1
    const int hl = lane & 31;                  // owns feats 4*hl .. 4*hl+3
    float a0 = 0.f, a1 = 0.f, a2 = 0.f, a3 = 0.f;
    float e0 = 0.f, e1 = 0.f, e2 = 0.f, e3 = 0.f, e4 = 0.f, e5 = 0.f;
    int i = pr.x;
    for (int bb = 0; bb < nb; ++bb, i += 8) {
        uint4 q[8];
#pragma unroll
        for (int j = 0; j < 8; ++j) q[j] = rec[i + j];           // SGPR, wave-uniform
        uint2 u[4];
#pragma unroll
        for (int p = 0; p < 4; ++p) {
            const unsigned int sA = q[2 * p].x & 0xFFFFu;
            const unsigned int sB = q[2 * p + 1].x & 0xFFFFu;
            const unsigned int s = half ? sB : sA;
            u[p] = reinterpret_cast<const uint2*>(nfb + (size_t)s * IN_F)[hl];
        }
#pragma unroll
        for (int p = 0; p < 4; ++p) {
            a0 += bf2f((unsigned short)u[p].x);
            a1 += bf2f((unsigned short)(u[p].x >> 16));
            a2 += bf2f((unsigned short)u[p].y);
            a3 += bf2f((unsigned short)(u[p].y >> 16));
        }
#pragma unroll
        for (int j = 0; j < 8; ++j) {
            e0 += bf2f((unsigned short)q[j].y);
            e1 += bf2f((unsigned short)(q[j].y >> 16));
            e2 += bf2f((unsigned short)q[j].z);
            e3 += bf2f((unsigned short)(q[j].z >> 16));
            e4 += bf2f((unsigned short)q[j].w);
            e5 += bf2f((unsigned short)(q[j].w >> 16));
        }
    }
    // fold the two half-wave partials (feats only; e-sums were whole-wave)
    a0 += __shfl_xor(a0, 32, 64);
    a1 += __shfl_xor(a1, 32, 64);
    a2 += __shfl_xor(a2, 32, 64);
    a3 += __shfl_xor(a3, 32, 64);
    if (half == 0) {
        uint2 o;
        o.x = packbf(a0, a1);
        o.y = packbf(a2, a3);
        reinterpret_cast<uint2*>(S + (size_t)n * IN_F)[hl] = o;   // 256B row, 32 lanes
    }
    if (lane == 0) {
        uint4 q;
        q.x = packbf(e0, e1);
        q.y = packbf(e2, e3);
        q.z = packbf(e4, e5);
        q.w = packbf((float)deg, 0.f);          // deg exact in bf16 (small)
        *reinterpret_cast<uint4*>(E8 + (size_t)n * 8) = q;
    }
}

// ---- K4: MFMA GEMM  out = relu( S[N,128]bf16 @ W[128,128]bf16 + E-term ) ----
__global__ __launch_bounds__(256) void gemm_mfma(
        const unsigned short* __restrict__ S, const unsigned short* __restrict__ E8,
        const unsigned short* __restrict__ Wpack, const float* __restrict__ W2pack,
        float* __restrict__ out, int n_nodes) {
    __shared__ __align__(16) short Wl[16384];   // 32 KB, B-fragment layout
    __shared__ float W2l[1024];                 // 4 KB
    const int tid = threadIdx.x;
    for (int i = tid; i < 2048; i += 256)
        reinterpret_cast<uint4*>(Wl)[i] = reinterpret_cast<const uint4*>(Wpack)[i];
    for (int i = tid; i < 1024; i += 256) W2l[i] = W2pack[i];

    const int wv = tid >> 6, lane = tid & 63;
    const int m = lane & 15, quad = lane >> 4;
    const int n0 = blockIdx.x * 64 + wv * 16;

    const int arow = min(n0 + m, n_nodes - 1);
    const unsigned short* ap = S + (size_t)arow * IN_F + quad * 8;
    bf16x8 a[4];
#pragma unroll
    for (int kb = 0; kb < 4; ++kb)
        a[kb] = *reinterpret_cast<const bf16x8*>(ap + kb * 32);

    __syncthreads();

    f32x4 acc[8];
#pragma unroll
    for (int ft = 0; ft < 8; ++ft) acc[ft] = (f32x4){0.f, 0.f, 0.f, 0.f};

#pragma unroll
    for (int kb = 0; kb < 4; ++kb) {
#pragma unroll
        for (int ft = 0; ft < 8; ++ft) {
            const bf16x8 bfrag =
                reinterpret_cast<const bf16x8*>(Wl)[(kb * 8 + ft) * 64 + lane];
            acc[ft] = __builtin_amdgcn_mfma_f32_16x16x32_bf16(a[kb], bfrag, acc[ft], 0, 0, 0);
        }
    }

    // Epilogue. C/D layout: col=lane&15, row=quad*4+reg.
    float e[4][7];
#pragma unroll
    for (int r = 0; r < 4; ++r) {
        const int n = min(n0 + quad * 4 + r, n_nodes - 1);
        const uint4 q = *reinterpret_cast<const uint4*>(E8 + (size_t)n * 8);
        e[r][0] = bf2f((unsigned short)q.x); e[r][1] = bf2f((unsigned short)(q.x >> 16));
        e[r][2] = bf2f((unsigned short)q.y); e[r][3] = bf2f((unsigned short)(q.y >> 16));
        e[r][4] = bf2f((unsigned short)q.z); e[r][5] = bf2f((unsigned short)(q.z >> 16));
        e[r][6] = bf2f((unsigned short)q.w);  // deg
    }
#pragma unroll
    for (int ft = 0; ft < 8; ++ft) {
        const int f = ft * 16 + m;
        float w2[7];
#pragma unroll
        for (int j = 0; j < 7; ++j) w2[j] = W2l[j * 128 + f];
#pragma unroll
        for (int r = 0; r < 4; ++r) {
            const int n = n0 + quad * 4 + r;
            if (n < n_nodes) {
                float v = acc[ft][r];
#pragma unroll
                for (int j = 0; j < 7; ++j) v += e[r][j] * w2[j];
                out[(size_t)n * 128 + f] = fmaxf(v, 0.f);
            }
        }
    }
}

extern "C" void kernel_launch(void* const* d_in, const int* in_sizes, int n_in,
                              void* d_out, int out_size, void* d_ws, size_t ws_size,
                              hipStream_t stream) {
    const float* nf = (const float*)d_in[0];  // fp32 (N,128)
    const int* eidx = (const int*)d_in[1];    // int32 (E,2)
    const float* ef = (const float*)d_in[2];  // fp32 (E,6)
    const float* W  = (const float*)d_in[3];  // fp32 (128,128)
    const float* b  = (const float*)d_in[4];  // fp32 (128,)
    const float* We = (const float*)d_in[5];  // fp32 (6,128)
    const float* be = (const float*)d_in[6];  // fp32 (128,)
    float* out = (float*)d_out;               // fp32 (N,128)

    const int n_nodes = in_sizes[0] / IN_F;
    const int n_edges = in_sizes[1] / 2;

    const int nblk_e = (n_edges + TILE_E - 1) / TILE_E;   // 196 sort blocks (<=256 req'd)
    const int nbin = (n_nodes + 255) >> 8;                // 196 fine buckets
    const int n_cast = n_nodes * (IN_F / 8);

    // ws (~66 MB): rec (nbin*BCAP recs, static padded layout) | rec_c
    //   (nblk_e*TILE_E recs, block-segmented) | S | E8 | Wpack | W2pack
    //   | pr2 | pmat | lmat | nfb ((N+1) rows). gbase is GONE.
    uint4* rec   = (uint4*)d_ws;
    uint4* rec_c = rec + (size_t)nbin * BCAP;
    unsigned short* S = (unsigned short*)(rec_c + (size_t)nblk_e * TILE_E);
    unsigned short* E8 = S + (size_t)n_nodes * IN_F;
    unsigned short* Wpack = E8 + (size_t)n_nodes * 8;
    float* W2pack = (float*)(Wpack + 16384);
    int2* pr2 = (int2*)(W2pack + 1024);
    unsigned short* pmat = (unsigned short*)(pr2 + n_nodes);
    unsigned short* lmat = pmat + (size_t)nblk_e * NBIN_PAD;
    unsigned short* nfb = lmat + (size_t)nblk_e * NBIN_PAD;

    // No memset needed: pmat/lmat rows fully written by sort blocks, rec/rec_c
    // read only within written bounds, pad records explicitly written.
    sort_pack_cast<<<nblk_e + 1 + CAST_B, 256, 0, stream>>>(
        eidx, ef, rec_c, pmat, lmat, n_edges, nblk_e, n_cast, n_nodes,
        nf, nfb, W, b, We, be, Wpack, W2pack);
    fine_rank<<<nbin, 256, 0, stream>>>(rec_c, pmat, lmat, rec, pr2,
                                        n_nodes, nblk_e);
    aggregate_bf16<<<(n_nodes + 3) / 4, 256, 0, stream>>>(nfb, rec, pr2, S, E8, n_nodes);
    gemm_mfma<<<(n_nodes + 63) / 64, 256, 0, stream>>>(S, E8, Wpack, W2pack, out, n_nodes);
}

// Round 7
// 177.428 us; speedup vs baseline: 1.1093x; 1.1012x over previous
//
#include <hip/hip_runtime.h>
#include <hip/hip_bf16.h>
#include <stdint.h>

#define IN_F 128
#define EDGE_F 6
#define TILE_E 4096      // per-block sort tile (block-local, no cross-block mapping needed)
#define NBIN_PAD 256     // coarse bins = dst>>8 (n_nodes <= 65536; N=50000 -> 196 used)
#define BCAP 8192        // padded records per bucket (mean ~4082+pad<=1792; ~60 sigma margin)
#define IDXN 8192        // fine_rank LDS index capacity (bucket mean 4082, sigma ~64)
#define CAST_B 400       // dedicated cast blocks riding in the K1 grid

using bf16x8 = __attribute__((ext_vector_type(8))) short;  // 8 bf16 = 4 VGPRs
using f32x4  = __attribute__((ext_vector_type(4))) float;

__device__ __forceinline__ float bf2f(unsigned short u) {
    return __uint_as_float(((unsigned int)u) << 16);
}
__device__ __forceinline__ unsigned short f2bfbits(float f) {
    __hip_bfloat16 h = __float2bfloat16(f);  // RNE
    return *reinterpret_cast<unsigned short*>(&h);
}
__device__ __forceinline__ unsigned int packbf(float a, float b) {
    return ((unsigned int)f2bfbits(b) << 16) | (unsigned int)f2bfbits(a);
}

// ---- K1: block-LOCAL counting sort + inline pack + nf cast + weight pack ----
// Each sort block owns tile blk*TILE_E and its own output segment: LDS hist
// of 256 coarse bins, local scan, scatter packed records bin-grouped within
// its 64KB segment. No cross-block coordination. Cast blocks and the
// weight-pack block ride in the same grid (independent work).
__global__ __launch_bounds__(256) void sort_pack_cast(
        const int* __restrict__ eidx, const float* __restrict__ ef,
        uint4* __restrict__ rec_c, unsigned short* __restrict__ pmat,
        unsigned short* __restrict__ lmat,
        int n_edges, int nblk_e, int n_cast, int n_nodes,
        const float* __restrict__ nf, unsigned short* __restrict__ nfb,
        const float* __restrict__ W, const float* __restrict__ b,
        const float* __restrict__ We, const float* __restrict__ be,
        unsigned short* __restrict__ Wpack, float* __restrict__ W2pack) {
    const int tid = threadIdx.x;
    const int blk = blockIdx.x;
    __shared__ unsigned int qxs[TILE_E];   // 16 KB: packed src|dst<<16, staged once
    __shared__ int hist[NBIN_PAD];         // counts -> inclusive scan
    __shared__ int cur[NBIN_PAD];          // scatter cursors

    if (blk < nblk_e) {
        hist[tid] = 0;
        __syncthreads();
        const int e0 = blk * TILE_E;
        const int lim = min(TILE_E, n_edges - e0);
        // pass A: stage qx in LDS + LDS hist (eidx read ONCE)
        for (int i = tid; i < lim; i += 256) {
            const int2 pr = reinterpret_cast<const int2*>(eidx)[e0 + i];  // (src,dst)
            const unsigned int q = (unsigned int)pr.x | ((unsigned int)pr.y << 16);
            qxs[i] = q;
            atomicAdd(&hist[q >> 24], 1);          // q>>24 == dst>>8
        }
        __syncthreads();
        const int own = hist[tid];
        for (int off = 1; off < 256; off <<= 1) {  // inclusive scan of bin counts
            int t2 = (tid >= off) ? hist[tid - off] : 0;
            __syncthreads();
            hist[tid] += t2;
            __syncthreads();
        }
        const int excl = hist[tid] - own;          // local bin offset
        pmat[(size_t)blk * NBIN_PAD + tid] = (unsigned short)own;
        lmat[(size_t)blk * NBIN_PAD + tid] = (unsigned short)excl;
        cur[tid] = excl;
        __syncthreads();
        // pass B: read ef (coalesced), pack 16B record, scatter into OWN segment
        uint4* seg = rec_c + (size_t)blk * TILE_E;
        for (int i = tid; i < lim; i += 256) {
            const unsigned int q = qxs[i];
            const float2* efs = reinterpret_cast<const float2*>(ef + (size_t)(e0 + i) * EDGE_F);
            const float2 f0 = efs[0], f1 = efs[1], f2 = efs[2];
            uint4 r;
            r.x = q;
            r.y = packbf(f0.x, f0.y);
            r.z = packbf(f1.x, f1.y);
            r.w = packbf(f2.x, f2.y);
            const int pos = atomicAdd(&cur[q >> 24], 1);
            seg[pos] = r;                          // 64KB window, bin-grouped
        }
    } else if (blk == nblk_e) {
        // Wpack: idx=((kb*8+ft)*64+lane)*8+j -> bf16(W[kb*32+(lane>>4)*8+j][ft*16+(lane&15)])
        for (int idx = tid; idx < 16384; idx += 256) {
            int j = idx & 7, lane = (idx >> 3) & 63, ft = (idx >> 9) & 7, kb = idx >> 12;
            int k = kb * 32 + (lane >> 4) * 8 + j;
            int f = ft * 16 + (lane & 15);
            Wpack[idx] = f2bfbits(W[k * 128 + f]);
        }
        for (int idx = tid; idx < 1024; idx += 256) {
            int j = idx >> 7, f = idx & 127;
            float w = 0.f;
            if (j < 6)       w = We[j * 128 + f];
            else if (j == 6) w = b[f] + be[f];
            W2pack[idx] = w;
        }
        // dummy node row (index n_nodes): zero. Pad records gather from here.
        if (tid < 16) {
            uint4 z; z.x = z.y = z.z = z.w = 0u;
            reinterpret_cast<uint4*>(nfb + (size_t)n_nodes * IN_F)[tid] = z;
        }
    } else {
        // cast block: nf -> bf16, vectorized (uint4 in / uint4 out)
        const int cb = blk - nblk_e - 1;
        const int ncb = gridDim.x - nblk_e - 1;
        for (int i = cb * 256 + tid; i < n_cast; i += ncb * 256) {
            const float4 lo = reinterpret_cast<const float4*>(nf)[2 * i];
            const float4 hi = reinterpret_cast<const float4*>(nf)[2 * i + 1];
            uint4 o;
            o.x = packbf(lo.x, lo.y); o.y = packbf(lo.z, lo.w);
            o.z = packbf(hi.x, hi.y); o.w = packbf(hi.z, hi.w);
            reinterpret_cast<uint4*>(nfb)[i] = o;
        }
    }
}

// ---- K2: FLAT-PARALLEL bucket assembly + fine sort -> PADDED CSR rec + pr2 ----
// R6's version was latency-bound: 1 block/CU, 1 wave/SIMD, each thread walking
// its ~21-record run SERIALLY (dependent L2 load chains). New form: 512
// threads/bucket; scan the 196 run lengths; every record index is resolved by
// an 8-step LDS binary search; records processed in flat 4-deep independent
// batches (pipelined loads) in both passes. Linearized record indices cached
// in 32KB LDS between passes. Output at static base c*BCAP, runs padded to a
// multiple of 8 with dummy records (src=n_nodes -> zero row).
__global__ __launch_bounds__(512) void fine_rank(
        const uint4* __restrict__ rec_c, const unsigned short* __restrict__ pmat,
        const unsigned short* __restrict__ lmat,
        uint4* __restrict__ rec, int2* __restrict__ pr2,
        int n_nodes, int nblk_e) {
    const int tid = threadIdx.x;
    const int c = blockIdx.x;
    __shared__ int rstart[NBIN_PAD + 1];   // run-start prefix within bucket
    __shared__ int rbaseg[NBIN_PAD];       // global record idx of each run start
    __shared__ int fcnt[256];              // scratch: run scan, then dst hist/scan
    __shared__ int fpos[256];
    __shared__ int idxl[IDXN];             // 32 KB: linearized global record idx

    if (tid < 256) {
        const bool r = (tid < nblk_e);
        fcnt[tid] = r ? pmat[(size_t)tid * NBIN_PAD + c] : 0;
        rbaseg[tid] = tid * TILE_E + (r ? (int)lmat[(size_t)tid * NBIN_PAD + c] : 0);
    }
    __syncthreads();
    for (int off = 1; off < 256; off <<= 1) {   // inclusive scan of run lengths
        int v = 0;
        if (tid < 256 && tid >= off) v = fcnt[tid - off];
        __syncthreads();
        if (tid < 256) fcnt[tid] += v;
        __syncthreads();
    }
    if (tid < 256) rstart[tid + 1] = fcnt[tid];
    if (tid == 0) rstart[0] = 0;
    __syncthreads();
    int sz = rstart[256];
    if (sz > IDXN) sz = IDXN;                   // ~64-sigma impossible; guard only
    __syncthreads();
    if (tid < 256) fcnt[tid] = 0;
    __syncthreads();
    // pass 1: resolve indices (binary search), cache in LDS, dst histogram.
    for (int base = 0; base < sz; base += 2048) {
        int ii[4], g[4];
        unsigned int qx[4];
#pragma unroll
        for (int u = 0; u < 4; ++u) ii[u] = base + u * 512 + tid;
#pragma unroll
        for (int u = 0; u < 4; ++u) {
            if (ii[u] < sz) {
                int lo = 0, hi = 255;
                while (lo < hi) {               // max j with rstart[j] <= i
                    const int mid = (lo + hi + 1) >> 1;
                    if (rstart[mid] <= ii[u]) lo = mid; else hi = mid - 1;
                }
                g[u] = rbaseg[lo] + (ii[u] - rstart[lo]);
                idxl[ii[u]] = g[u];
            }
        }
#pragma unroll
        for (int u = 0; u < 4; ++u)             // 4 independent loads in flight
            if (ii[u] < sz)
                qx[u] = reinterpret_cast<const unsigned int*>(rec_c)[(size_t)g[u] * 4];
#pragma unroll
        for (int u = 0; u < 4; ++u)
            if (ii[u] < sz) atomicAdd(&fcnt[(qx[u] >> 16) & 255], 1);
    }
    __syncthreads();
    int own = 0, ownp = 0, pexcl = 0;
    if (tid < 256) { own = fcnt[tid]; ownp = (own + 7) & ~7; fcnt[tid] = ownp; }
    __syncthreads();
    for (int off = 1; off < 256; off <<= 1) {   // inclusive scan of padded lengths
        int v = 0;
        if (tid < 256 && tid >= off) v = fcnt[tid - off];
        __syncthreads();
        if (tid < 256) fcnt[tid] += v;
        __syncthreads();
    }
    const size_t obase = (size_t)c * BCAP;
    if (tid < 256) {
        pexcl = fcnt[tid] - ownp;
        fpos[tid] = pexcl;
        const int n = c * 256 + tid;
        if (n < n_nodes) {
            int2 pr; pr.x = (int)(obase + pexcl); pr.y = own;
            pr2[n] = pr;
        }
    }
    __syncthreads();
    // pass 2: ranked scatter via cached indices (4-deep batches).
    for (int base = 0; base < sz; base += 2048) {
        int ii[4];
        uint4 q[4];
#pragma unroll
        for (int u = 0; u < 4; ++u) ii[u] = base + u * 512 + tid;
#pragma unroll
        for (int u = 0; u < 4; ++u)
            if (ii[u] < sz) q[u] = rec_c[idxl[ii[u]]];
#pragma unroll
        for (int u = 0; u < 4; ++u) {
            if (ii[u] < sz) {
                const int r = atomicAdd(&fpos[(q[u].x >> 16) & 255], 1);
                if (r < BCAP) rec[obase + r] = q[u];
            }
        }
    }
    // pad fill: thread tid owns dst tid's <=7 dummy slots
    if (tid < 256) {
        uint4 dmy; dmy.x = (unsigned int)n_nodes; dmy.y = dmy.z = dmy.w = 0u;
        for (int j = own; j < ownp && pexcl + j < BCAP; ++j)
            rec[obase + pexcl + j] = dmy;
    }
}

// ---- K3: aggregate. One wave per dst; half-wave pair gather (8B/lane). ----
// rec[i] loads are wave-uniform -> SGPRs. Every dst run is a multiple of 8
// records; each batch issues 4 dwordx2 gathers covering 8 edges. The gather
// is TCC/LLC byte-throughput-bound (R2 scaling + R4 pad-null + R5 pair-null
// all agree) -- do not spend more rounds on its concurrency. Max-occupancy
// kernel; do NOT fuse with the MFMA gemm (R12).
__global__ __launch_bounds__(256) void aggregate_bf16(
        const unsigned short* __restrict__ nfb, const uint4* __restrict__ rec,
        const int2* __restrict__ pr2, unsigned short* __restrict__ S,
        unsigned short* __restrict__ E8, int n_nodes) {
    const int lane = threadIdx.x & 63;
    const int wv = __builtin_amdgcn_readfirstlane(threadIdx.x >> 6);
    const int n = blockIdx.x * 4 + wv;
    if (n >= n_nodes) return;
    const int2 pr = pr2[n];
    const int deg = pr.y;
    const int nb = (deg + 7) >> 3;             // all batches full (padded)
    const int half = lane >> 5;                // 0: edge 2p, 1: edge 2p+1
    const int hl = lane & 31;                  // owns feats 4*hl .. 4*hl+3
    float a0 = 0.f, a1 = 0.f, a2 = 0.f, a3 = 0.f;
    float e0 = 0.f, e1 = 0.f, e2 = 0.f, e3 = 0.f, e4 = 0.f, e5 = 0.f;
    int i = pr.x;
    for (int bb = 0; bb < nb; ++bb, i += 8) {
        uint4 q[8];
#pragma unroll
        for (int j = 0; j < 8; ++j) q[j] = rec[i + j];           // SGPR, wave-uniform
        uint2 u[4];
#pragma unroll
        for (int p = 0; p < 4; ++p) {
            const unsigned int sA = q[2 * p].x & 0xFFFFu;
            const unsigned int sB = q[2 * p + 1].x & 0xFFFFu;
            const unsigned int s = half ? sB : sA;
            u[p] = reinterpret_cast<const uint2*>(nfb + (size_t)s * IN_F)[hl];
        }
#pragma unroll
        for (int p = 0; p < 4; ++p) {
            a0 += bf2f((unsigned short)u[p].x);
            a1 += bf2f((unsigned short)(u[p].x >> 16));
            a2 += bf2f((unsigned short)u[p].y);
            a3 += bf2f((unsigned short)(u[p].y >> 16));
        }
#pragma unroll
        for (int j = 0; j < 8; ++j) {
            e0 += bf2f((unsigned short)q[j].y);
            e1 += bf2f((unsigned short)(q[j].y >> 16));
            e2 += bf2f((unsigned short)q[j].z);
            e3 += bf2f((unsigned short)(q[j].z >> 16));
            e4 += bf2f((unsigned short)q[j].w);
            e5 += bf2f((unsigned short)(q[j].w >> 16));
        }
    }
    // fold the two half-wave partials (feats only; e-sums were whole-wave)
    a0 += __shfl_xor(a0, 32, 64);
    a1 += __shfl_xor(a1, 32, 64);
    a2 += __shfl_xor(a2, 32, 64);
    a3 += __shfl_xor(a3, 32, 64);
    if (half == 0) {
        uint2 o;
        o.x = packbf(a0, a1);
        o.y = packbf(a2, a3);
        reinterpret_cast<uint2*>(S + (size_t)n * IN_F)[hl] = o;   // 256B row, 32 lanes
    }
    if (lane == 0) {
        uint4 q;
        q.x = packbf(e0, e1);
        q.y = packbf(e2, e3);
        q.z = packbf(e4, e5);
        q.w = packbf((float)deg, 0.f);          // deg exact in bf16 (small)
        *reinterpret_cast<uint4*>(E8 + (size_t)n * 8) = q;
    }
}

// ---- K4: MFMA GEMM  out = relu( S[N,128]bf16 @ W[128,128]bf16 + E-term ) ----
// NEW: coalesced epilogue. The old path did 32 scalar 4B stores/lane (64B
// segments) for the 25.6MB out stream. Now acc is staged into the dead Wl
// buffer (32KB fp32, reused post-MFMA) and streamed out as 16B/lane uint4.
__global__ __launch_bounds__(256) void gemm_mfma(
        const unsigned short* __restrict__ S, const unsigned short* __restrict__ E8,
        const unsigned short* __restrict__ Wpack, const float* __restrict__ W2pack,
        float* __restrict__ out, int n_nodes) {
    __shared__ __align__(16) short Wl[16384];   // 32 KB: B-fragments, then out-stage
    __shared__ float W2l[1024];                 // 4 KB
    const int tid = threadIdx.x;
    for (int i = tid; i < 2048; i += 256)
        reinterpret_cast<uint4*>(Wl)[i] = reinterpret_cast<const uint4*>(Wpack)[i];
    for (int i = tid; i < 1024; i += 256) W2l[i] = W2pack[i];

    const int wv = tid >> 6, lane = tid & 63;
    const int m = lane & 15, quad = lane >> 4;
    const int n0 = blockIdx.x * 64 + wv * 16;

    const int arow = min(n0 + m, n_nodes - 1);
    const unsigned short* ap = S + (size_t)arow * IN_F + quad * 8;
    bf16x8 a[4];
#pragma unroll
    for (int kb = 0; kb < 4; ++kb)
        a[kb] = *reinterpret_cast<const bf16x8*>(ap + kb * 32);

    __syncthreads();

    f32x4 acc[8];
#pragma unroll
    for (int ft = 0; ft < 8; ++ft) acc[ft] = (f32x4){0.f, 0.f, 0.f, 0.f};

#pragma unroll
    for (int kb = 0; kb < 4; ++kb) {
#pragma unroll
        for (int ft = 0; ft < 8; ++ft) {
            const bf16x8 bfrag =
                reinterpret_cast<const bf16x8*>(Wl)[(kb * 8 + ft) * 64 + lane];
            acc[ft] = __builtin_amdgcn_mfma_f32_16x16x32_bf16(a[kb], bfrag, acc[ft], 0, 0, 0);
        }
    }

    // Epilogue. C/D layout: col=lane&15, row=quad*4+reg.
    float e[4][7];
#pragma unroll
    for (int r = 0; r < 4; ++r) {
        const int n = min(n0 + quad * 4 + r, n_nodes - 1);
        const uint4 q = *reinterpret_cast<const uint4*>(E8 + (size_t)n * 8);
        e[r][0] = bf2f((unsigned short)q.x); e[r][1] = bf2f((unsigned short)(q.x >> 16));
        e[r][2] = bf2f((unsigned short)q.y); e[r][3] = bf2f((unsigned short)(q.y >> 16));
        e[r][4] = bf2f((unsigned short)q.z); e[r][5] = bf2f((unsigned short)(q.z >> 16));
        e[r][6] = bf2f((unsigned short)q.w);  // deg
    }
    __syncthreads();                            // Wl B-fragment reads complete
    float* So = reinterpret_cast<float*>(Wl);   // 64 rows x 128 f32 = 32 KB
#pragma unroll
    for (int ft = 0; ft < 8; ++ft) {
        const int f = ft * 16 + m;
        float w2[7];
#pragma unroll
        for (int j = 0; j < 7; ++j) w2[j] = W2l[j * 128 + f];
#pragma unroll
        for (int r = 0; r < 4; ++r) {
            float v = acc[ft][r];
#pragma unroll
            for (int j = 0; j < 7; ++j) v += e[r][j] * w2[j];
            So[(wv * 16 + quad * 4 + r) * 128 + f] = fmaxf(v, 0.f);
        }
    }
    __syncthreads();
    const size_t nb0 = (size_t)blockIdx.x * 64;
    for (int i = tid; i < 2048; i += 256) {     // 16B/lane, fully coalesced
        const int row = i >> 5;
        if (nb0 + row < (size_t)n_nodes)
            reinterpret_cast<uint4*>(out)[(nb0 + row) * 32 + (i & 31)] =
                reinterpret_cast<const uint4*>(So)[i];
    }
}

extern "C" void kernel_launch(void* const* d_in, const int* in_sizes, int n_in,
                              void* d_out, int out_size, void* d_ws, size_t ws_size,
                              hipStream_t stream) {
    const float* nf = (const float*)d_in[0];  // fp32 (N,128)
    const int* eidx = (const int*)d_in[1];    // int32 (E,2)
    const float* ef = (const float*)d_in[2];  // fp32 (E,6)
    const float* W  = (const float*)d_in[3];  // fp32 (128,128)
    const float* b  = (const float*)d_in[4];  // fp32 (128,)
    const float* We = (const float*)d_in[5];  // fp32 (6,128)
    const float* be = (const float*)d_in[6];  // fp32 (128,)
    float* out = (float*)d_out;               // fp32 (N,128)

    const int n_nodes = in_sizes[0] / IN_F;
    const int n_edges = in_sizes[1] / 2;

    const int nblk_e = (n_edges + TILE_E - 1) / TILE_E;   // 196 sort blocks (<=256 req'd)
    const int nbin = (n_nodes + 255) >> 8;                // 196 fine buckets
    const int n_cast = n_nodes * (IN_F / 8);

    // ws (~66 MB): rec (nbin*BCAP recs, static padded layout) | rec_c
    //   (nblk_e*TILE_E recs, block-segmented) | S | E8 | Wpack | W2pack
    //   | pr2 | pmat | lmat | nfb ((N+1) rows)
    uint4* rec   = (uint4*)d_ws;
    uint4* rec_c = rec + (size_t)nbin * BCAP;
    unsigned short* S = (unsigned short*)(rec_c + (size_t)nblk_e * TILE_E);
    unsigned short* E8 = S + (size_t)n_nodes * IN_F;
    unsigned short* Wpack = E8 + (size_t)n_nodes * 8;
    float* W2pack = (float*)(Wpack + 16384);
    int2* pr2 = (int2*)(W2pack + 1024);
    unsigned short* pmat = (unsigned short*)(pr2 + n_nodes);
    unsigned short* lmat = pmat + (size_t)nblk_e * NBIN_PAD;
    unsigned short* nfb = lmat + (size_t)nblk_e * NBIN_PAD;

    // No memset needed: pmat/lmat rows fully written by sort blocks, rec/rec_c
    // read only within written bounds, pad records explicitly written.
    sort_pack_cast<<<nblk_e + 1 + CAST_B, 256, 0, stream>>>(
        eidx, ef, rec_c, pmat, lmat, n_edges, nblk_e, n_cast, n_nodes,
        nf, nfb, W, b, We, be, Wpack, W2pack);
    fine_rank<<<nbin, 512, 0, stream>>>(rec_c, pmat, lmat, rec, pr2,
                                        n_nodes, nblk_e);
    aggregate_bf16<<<(n_nodes + 3) / 4, 256, 0, stream>>>(nfb, rec, pr2, S, E8, n_nodes);
    gemm_mfma<<<(n_nodes + 63) / 64, 256, 0, stream>>>(S, E8, Wpack, W2pack, out, n_nodes);
}